// Round 1
// baseline (5400.841 us; speedup 1.0000x reference)
//
#include <hip/hip_runtime.h>
#include <math.h>

#define NN 20000
#define GG 8
#define NPG 2500
#define EE 640000
#define CC 64
#define SSP 8
#define NBASIS 8
#define NLAYERS 3
#define CUTR 6.0f
#define AVGN 32.0f

__device__ __forceinline__ float silu_f(float x){ return x / (1.0f + __expf(-x)); }

// ---------------- edge geometry: y1, bessel feats, mask ----------------
__global__ void k_edge_geom(const float* __restrict__ pos, const float* __restrict__ cell,
                            const float* __restrict__ Sij, const int* __restrict__ ei,
                            const int* __restrict__ batch,
                            float* __restrict__ y1A, float* __restrict__ efeat,
                            float* __restrict__ maskA)
{
  int e = blockIdx.x * 256 + threadIdx.x;
  if (e >= EE) return;
  int snd = ei[e], rcv = ei[EE + e];
  int g = batch[snd];
  float s0 = Sij[e*3+0], s1 = Sij[e*3+1], s2 = Sij[e*3+2];
  const float* cg = cell + g*9;
  float R[3];
  #pragma unroll
  for (int j = 0; j < 3; ++j) {
    float shift = s0*cg[0*3+j] + s1*cg[1*3+j] + s2*cg[2*3+j];
    R[j] = (pos[rcv*3+j] - pos[snd*3+j] + shift) * (1.0f/CUTR);
  }
  float len = sqrtf(R[0]*R[0] + R[1]*R[1] + R[2]*R[2]);
  float mk   = (len > 0.0f) ? 1.0f : 0.0f;
  float safe = (len > 0.0f) ? len  : 1.0f;
  float inv  = 1.0f / safe;
  const float sqrt3 = 1.7320508075688772f;
  y1A[e*3+0] = sqrt3*R[0]*inv;
  y1A[e*3+1] = sqrt3*R[1]*inv;
  y1A[e*3+2] = sqrt3*R[2]*inv;
  float x = safe;
  float env = (x < 1.0f) ? (1.0f - 6.0f*x*x + 8.0f*x*x*x - 3.0f*x*x*x*x) : 0.0f;
  float emk = env * mk;
  const float sqrt2 = 1.4142135623730951f;
  const float PI_F = 3.14159265358979323846f;
  #pragma unroll
  for (int n = 1; n <= NBASIS; ++n)
    efeat[e*8 + n - 1] = sqrt2 * __sinf(PI_F * (float)n * safe) * inv * emk;
  maskA[e] = mk;
}

// ---------------- CSR build ----------------
__global__ void k_count(const int* __restrict__ ei, int* __restrict__ deg)
{
  int e = blockIdx.x * 256 + threadIdx.x;
  if (e >= EE) return;
  atomicAdd(&deg[ei[EE + e]], 1);
}

__global__ void k_scan(const int* __restrict__ deg, int* __restrict__ rowptr,
                       int* __restrict__ cursor)
{
  __shared__ int buf[1024];
  __shared__ int carry;
  int tid = threadIdx.x;
  if (tid == 0) carry = 0;
  __syncthreads();
  for (int base = 0; base < NN; base += 1024) {
    int i = base + tid;
    int x = (i < NN) ? deg[i] : 0;
    buf[tid] = x; __syncthreads();
    for (int off = 1; off < 1024; off <<= 1) {
      int t = (tid >= off) ? buf[tid - off] : 0;
      __syncthreads();
      buf[tid] += t;
      __syncthreads();
    }
    int incl = buf[tid];
    int c = carry;
    __syncthreads();
    if (i < NN) { rowptr[i] = c + incl - x; cursor[i] = c + incl - x; }
    if (tid == 1023) carry = c + incl;
    __syncthreads();
  }
  if (tid == 0) rowptr[NN] = carry;
}

__global__ void k_scatter(const int* __restrict__ ei, int* __restrict__ cursor,
                          int* __restrict__ csr)
{
  int e = blockIdx.x * 256 + threadIdx.x;
  if (e >= EE) return;
  int slot = atomicAdd(&cursor[ei[EE + e]], 1);
  csr[slot] = e;
}

// ---------------- embedding ----------------
__global__ void k_xf_table(const float* __restrict__ W_embed, const float* __restrict__ W_x,
                           float* __restrict__ T)
{
  int sp = threadIdx.x >> 6, o = threadIdx.x & 63;
  float acc = 0.0f;
  for (int c = 0; c < 64; ++c) acc += W_embed[sp*64 + c] * W_x[c*64 + o];
  T[threadIdx.x] = acc;
}

__global__ void k_embed(const int* __restrict__ species, const float* __restrict__ W_embed,
                        const float* __restrict__ T, float* __restrict__ s,
                        float* __restrict__ xf)
{
  int gid = blockIdx.x * 256 + threadIdx.x;
  if (gid >= NN * 64) return;
  int n = gid >> 6, c = gid & 63;
  int sp = species[n];
  s[gid]  = W_embed[sp*64 + c];
  xf[gid] = T[sp*64 + c];
}

// ---------------- per-layer: up-projection ----------------
__global__ void k_up(const float* __restrict__ s, const float* __restrict__ v,
                     const float* __restrict__ Wus, const float* __restrict__ Wuv,
                     float* __restrict__ s_up, float* __restrict__ v_up)
{
  int gid = blockIdx.x * 256 + threadIdx.x;
  if (gid >= NN * 64) return;
  int n = gid >> 6, o = gid & 63;
  const float* sn = s + n*64;
  float acc = 0.0f;
  for (int c = 0; c < 64; ++c) acc += sn[c] * Wus[c*64 + o];
  s_up[gid] = acc;
  #pragma unroll
  for (int m = 0; m < 3; ++m) {
    const float* vn = v + (n*3 + m)*64;
    float a = 0.0f;
    for (int c = 0; c < 64; ++c) a += vn[c] * Wuv[c*64 + o];
    v_up[(n*3 + m)*64 + o] = a;
  }
}

// ---------------- per-layer: gather (radial MLP + messages + aggregation) ----------------
// block = 1024 (16 waves), wave-per-node, weights staged in LDS (~92 KB; gfx950 WG LDS limit 160 KB)
__global__ __launch_bounds__(1024, 1) void k_gather(
    const int* __restrict__ ei, const int* __restrict__ rowptr, const int* __restrict__ csr,
    const float* __restrict__ efeat, const float* __restrict__ y1A, const float* __restrict__ maskA,
    const float* __restrict__ s_up, const float* __restrict__ v_up,
    const float* __restrict__ Wr1, const float* __restrict__ br1,
    const float* __restrict__ Wr2, const float* __restrict__ br2,
    const float* __restrict__ Wr3,
    float* __restrict__ agg_s, float* __restrict__ agg_v)
{
  __shared__ float sm[23168];   // 512 + 64 + 4096 + 64 + 16384 + 1024 + 1024 floats
  float* Wr1s = sm;
  float* br1s = sm + 512;
  float* Wr2s = sm + 576;
  float* br2s = sm + 4672;
  float* Wr3s = sm + 4736;
  float* h1b  = sm + 21120;
  float* h2b  = sm + 22144;
  int tid = threadIdx.x;
  for (int i = tid; i < 512;   i += 1024) Wr1s[i] = Wr1[i];
  for (int i = tid; i < 64;    i += 1024) { br1s[i] = br1[i]; br2s[i] = br2[i]; }
  for (int i = tid; i < 4096;  i += 1024) Wr2s[i] = Wr2[i];
  for (int i = tid; i < 16384; i += 1024) Wr3s[i] = Wr3[i];
  __syncthreads();

  int w = tid >> 6, c = tid & 63;
  int r = blockIdx.x * 16 + w;
  if (r >= NN) return;
  int start = rowptr[r], end = rowptr[r + 1];
  float accs = 0.0f, av0 = 0.0f, av1 = 0.0f, av2 = 0.0f;
  float* h1w = h1b + w*64;
  float* h2w = h2b + w*64;
  const float inv_sqrt3 = 0.5773502691896258f;

  for (int idx = start; idx < end; ++idx) {
    int e = csr[idx];
    const float* fe = efeat + (size_t)e * 8;
    float h1 = br1s[c];
    #pragma unroll
    for (int b = 0; b < 8; ++b) h1 += fe[b] * Wr1s[b*64 + c];
    h1 = silu_f(h1);
    h1w[c] = h1;                      // wave-lockstep cross-lane via LDS (no barrier needed)
    float h2 = br2s[c];
    for (int k = 0; k < 64; ++k) h2 += h1w[k] * Wr2s[k*64 + c];
    h2 = silu_f(h2);
    h2w[c] = h2;
    float w0 = 0.0f, w1 = 0.0f, w2 = 0.0f, w3 = 0.0f;
    for (int k = 0; k < 64; ++k) {
      float h = h2w[k];
      const float* wr = Wr3s + k*256;
      w0 += h * wr[c];
      w1 += h * wr[64 + c];
      w2 += h * wr[128 + c];
      w3 += h * wr[192 + c];
    }
    float mk = maskA[e];
    w0 *= mk; w1 *= mk; w2 *= mk; w3 *= mk;
    int sn = ei[e];
    float ss  = s_up[sn*64 + c];
    float vv0 = v_up[(sn*3 + 0)*64 + c];
    float vv1 = v_up[(sn*3 + 1)*64 + c];
    float vv2 = v_up[(sn*3 + 2)*64 + c];
    float yy0 = y1A[e*3 + 0], yy1 = y1A[e*3 + 1], yy2 = y1A[e*3 + 2];
    float dot = vv0*yy0 + vv1*yy1 + vv2*yy2;
    accs += w0*ss + w1*dot*inv_sqrt3;
    av0  += w2*ss*yy0 + w3*vv0;
    av1  += w2*ss*yy1 + w3*vv1;
    av2  += w2*ss*yy2 + w3*vv2;
  }
  const float invavg = 1.0f / AVGN;
  agg_s[r*64 + c]          = accs * invavg;
  agg_v[(r*3 + 0)*64 + c]  = av0 * invavg;
  agg_v[(r*3 + 1)*64 + c]  = av1 * invavg;
  agg_v[(r*3 + 2)*64 + c]  = av2 * invavg;
}

// ---------------- per-layer: post (msg/sc/product matvecs + fused readout) ----------------
__global__ __launch_bounds__(512) void k_post(
    const float* __restrict__ agg_s, const float* __restrict__ agg_v,
    const float* __restrict__ xf, const int* __restrict__ species,
    float* __restrict__ s, float* __restrict__ v,
    const float* __restrict__ Wms, const float* __restrict__ Wmv,
    const float* __restrict__ Wscs, const float* __restrict__ Wscv,
    const float* __restrict__ Wps, const float* __restrict__ Wpv,
    const float* __restrict__ Wread, float* __restrict__ acc_out)
{
  __shared__ float tsb[8*64];
  __shared__ float tvb[8*3*64];
  __shared__ float vnb[8*3*64];
  int tid = threadIdx.x;
  int w = tid >> 6, c = tid & 63;
  int n = blockIdx.x * 8 + w;
  if (n >= NN) return;
  int sp = species[n];
  const float* as = agg_s + n*64;
  float ms = 0.0f;
  for (int k = 0; k < 64; ++k) ms += as[k] * Wms[k*64 + c];
  float xfc = xf[n*64 + c];
  tsb[w*64 + c] = xfc * ms;
  #pragma unroll
  for (int m = 0; m < 3; ++m) {
    const float* av = agg_v + (n*3 + m)*64;
    float mv = 0.0f;
    for (int k = 0; k < 64; ++k) mv += av[k] * Wmv[k*64 + c];
    tvb[(w*3 + m)*64 + c] = xfc * mv;
  }
  const float* snp = s + n*64;
  const float* Wsc_s = Wscs + sp*4096;
  float snew = 0.0f;
  {
    const float* tw = tsb + w*64;
    for (int k = 0; k < 64; ++k) snew += tw[k] * Wps[k*64 + c];
    for (int k = 0; k < 64; ++k) snew += snp[k] * Wsc_s[k*64 + c];
  }
  const float* Wsc_v = Wscv + sp*4096;
  float vnew[3];
  #pragma unroll
  for (int m = 0; m < 3; ++m) {
    const float* tw = tvb + (w*3 + m)*64;
    const float* vn = v + (n*3 + m)*64;
    float a = 0.0f;
    for (int k = 0; k < 64; ++k) a += tw[k] * Wpv[k*64 + c];
    for (int k = 0; k < 64; ++k) a += vn[k] * Wsc_v[k*64 + c];
    vnew[m] = a;
    vnb[(w*3 + m)*64 + c] = a;
  }
  s[n*64 + c] = snew;                       // safe: snew data-depends on all reads of s-row
  #pragma unroll
  for (int m = 0; m < 3; ++m) v[(n*3 + m)*64 + c] = vnew[m];
  if (c < 9) {                              // readout, fused silu-accumulate across layers
    int o3 = c / 3, m = c % 3;
    const float* vb = vnb + (w*3 + m)*64;
    const float* wr = Wread + o3*64;
    float a = 0.0f;
    for (int k = 0; k < 64; ++k) a += vb[k] * wr[k];
    acc_out[n*9 + c] += silu_f(a);
  }
}

// ---------------- final graph reduction ----------------
__global__ void k_final(const float* __restrict__ acc_out, float* __restrict__ out)
{
  __shared__ float red[256];
  int g = blockIdx.x / 9, j = blockIdx.x % 9;
  int tid = threadIdx.x;
  float a = 0.0f;
  for (int n = g*NPG + tid; n < (g + 1)*NPG; n += 256) a += acc_out[n*9 + j];
  red[tid] = a; __syncthreads();
  for (int off = 128; off > 0; off >>= 1) {
    if (tid < off) red[tid] += red[tid + off];
    __syncthreads();
  }
  if (tid == 0) out[g*9 + j] = red[0];
}

extern "C" void kernel_launch(void* const* d_in, const int* in_sizes, int n_in,
                              void* d_out, int out_size, void* d_ws, size_t ws_size,
                              hipStream_t stream)
{
  const float* pos     = (const float*)d_in[0];
  const float* cell    = (const float*)d_in[1];
  const float* Sij     = (const float*)d_in[2];
  const float* W_embed = (const float*)d_in[3];
  const float* W_x     = (const float*)d_in[4];
  const float* W_up_s  = (const float*)d_in[5];
  const float* W_up_v  = (const float*)d_in[6];
  const float* Wr1     = (const float*)d_in[7];
  const float* br1     = (const float*)d_in[8];
  const float* Wr2     = (const float*)d_in[9];
  const float* br2     = (const float*)d_in[10];
  const float* Wr3     = (const float*)d_in[11];
  const float* W_msg_s = (const float*)d_in[12];
  const float* W_msg_v = (const float*)d_in[13];
  const float* W_sc_s  = (const float*)d_in[14];
  const float* W_sc_v  = (const float*)d_in[15];
  const float* W_p_s   = (const float*)d_in[16];
  const float* W_p_v   = (const float*)d_in[17];
  const float* W_read  = (const float*)d_in[18];
  const int*   ei      = (const int*)d_in[19];
  const int*   batch   = (const int*)d_in[20];
  const int*   species = (const int*)d_in[21];
  float* out = (float*)d_out;

  char* ws = (char*)d_ws;
  size_t off = 0;
  auto alloc = [&](size_t bytes) -> void* {
    void* p = ws + off;
    off += (bytes + 255) & ~(size_t)255;
    return p;
  };
  float* y1A     = (float*)alloc((size_t)EE*3*4);
  float* efeat   = (float*)alloc((size_t)EE*8*4);
  float* maskA   = (float*)alloc((size_t)EE*4);
  float* sF      = (float*)alloc((size_t)NN*64*4);
  float* vF      = (float*)alloc((size_t)NN*192*4);
  float* xfF     = (float*)alloc((size_t)NN*64*4);
  float* s_up    = (float*)alloc((size_t)NN*64*4);
  float* v_up    = (float*)alloc((size_t)NN*192*4);
  float* agg_s   = (float*)alloc((size_t)NN*64*4);
  float* agg_v   = (float*)alloc((size_t)NN*192*4);
  float* acc_out = (float*)alloc((size_t)NN*9*4);
  float* T       = (float*)alloc(512*4);
  int* deg    = (int*)alloc((size_t)NN*4);
  int* rowptr = (int*)alloc((size_t)(NN+1)*4);
  int* cursor = (int*)alloc((size_t)NN*4);
  int* csr    = (int*)alloc((size_t)EE*4);

  hipMemsetAsync(deg, 0, (size_t)NN*4, stream);
  hipMemsetAsync(vF, 0, (size_t)NN*192*4, stream);
  hipMemsetAsync(acc_out, 0, (size_t)NN*9*4, stream);

  k_edge_geom<<<EE/256, 256, 0, stream>>>(pos, cell, Sij, ei, batch, y1A, efeat, maskA);
  k_count   <<<EE/256, 256, 0, stream>>>(ei, deg);
  k_scan    <<<1, 1024, 0, stream>>>(deg, rowptr, cursor);
  k_scatter <<<EE/256, 256, 0, stream>>>(ei, cursor, csr);
  k_xf_table<<<1, 512, 0, stream>>>(W_embed, W_x, T);
  k_embed   <<<NN*64/256, 256, 0, stream>>>(species, W_embed, T, sF, xfF);

  for (int l = 0; l < NLAYERS; ++l) {
    k_up<<<NN*64/256, 256, 0, stream>>>(sF, vF, W_up_s + l*4096, W_up_v + l*4096, s_up, v_up);
    k_gather<<<1250, 1024, 0, stream>>>(ei, rowptr, csr, efeat, y1A, maskA, s_up, v_up,
                                        Wr1 + l*512, br1 + l*64, Wr2 + l*4096, br2 + l*64,
                                        Wr3 + l*16384, agg_s, agg_v);
    k_post<<<2500, 512, 0, stream>>>(agg_s, agg_v, xfF, species, sF, vF,
                                     W_msg_s + l*4096, W_msg_v + l*4096,
                                     W_sc_s + l*32768, W_sc_v + l*32768,
                                     W_p_s + l*4096, W_p_v + l*4096,
                                     W_read + l*192, acc_out);
  }
  k_final<<<72, 256, 0, stream>>>(acc_out, out);
}

// Round 2
// 2954.932 us; speedup vs baseline: 1.8277x; 1.8277x over previous
//
#include <hip/hip_runtime.h>
#include <math.h>

#define NN 20000
#define GG 8
#define NPG 2500
#define EE 640000
#define CC 64
#define SSP 8
#define NBASIS 8
#define NLAYERS 3
#define CUTR 6.0f
#define AVGN 32.0f

__device__ __forceinline__ float silu_f(float x){ return x / (1.0f + __expf(-x)); }

// ---------------- edge geometry: y1, bessel feats, mask ----------------
__global__ void k_edge_geom(const float* __restrict__ pos, const float* __restrict__ cell,
                            const float* __restrict__ Sij, const int* __restrict__ ei,
                            const int* __restrict__ batch,
                            float* __restrict__ y1A, float* __restrict__ efeat,
                            float* __restrict__ maskA)
{
  int e = blockIdx.x * 256 + threadIdx.x;
  if (e >= EE) return;
  int snd = ei[e], rcv = ei[EE + e];
  int g = batch[snd];
  float s0 = Sij[e*3+0], s1 = Sij[e*3+1], s2 = Sij[e*3+2];
  const float* cg = cell + g*9;
  float R[3];
  #pragma unroll
  for (int j = 0; j < 3; ++j) {
    float shift = s0*cg[0*3+j] + s1*cg[1*3+j] + s2*cg[2*3+j];
    R[j] = (pos[rcv*3+j] - pos[snd*3+j] + shift) * (1.0f/CUTR);
  }
  float len = sqrtf(R[0]*R[0] + R[1]*R[1] + R[2]*R[2]);
  float mk   = (len > 0.0f) ? 1.0f : 0.0f;
  float safe = (len > 0.0f) ? len  : 1.0f;
  float inv  = 1.0f / safe;
  const float sqrt3 = 1.7320508075688772f;
  y1A[e*3+0] = sqrt3*R[0]*inv;
  y1A[e*3+1] = sqrt3*R[1]*inv;
  y1A[e*3+2] = sqrt3*R[2]*inv;
  float x = safe;
  float env = (x < 1.0f) ? (1.0f - 6.0f*x*x + 8.0f*x*x*x - 3.0f*x*x*x*x) : 0.0f;
  float emk = env * mk;
  const float sqrt2 = 1.4142135623730951f;
  const float PI_F = 3.14159265358979323846f;
  #pragma unroll
  for (int n = 1; n <= NBASIS; ++n)
    efeat[e*8 + n - 1] = sqrt2 * __sinf(PI_F * (float)n * safe) * inv * emk;
  maskA[e] = mk;
}

// ---------------- CSR build ----------------
__global__ void k_count(const int* __restrict__ ei, int* __restrict__ deg)
{
  int e = blockIdx.x * 256 + threadIdx.x;
  if (e >= EE) return;
  atomicAdd(&deg[ei[EE + e]], 1);
}

__global__ void k_scan(const int* __restrict__ deg, int* __restrict__ rowptr,
                       int* __restrict__ cursor)
{
  __shared__ int buf[1024];
  __shared__ int carry;
  int tid = threadIdx.x;
  if (tid == 0) carry = 0;
  __syncthreads();
  for (int base = 0; base < NN; base += 1024) {
    int i = base + tid;
    int x = (i < NN) ? deg[i] : 0;
    buf[tid] = x; __syncthreads();
    for (int off = 1; off < 1024; off <<= 1) {
      int t = (tid >= off) ? buf[tid - off] : 0;
      __syncthreads();
      buf[tid] += t;
      __syncthreads();
    }
    int incl = buf[tid];
    int c = carry;
    __syncthreads();
    if (i < NN) { rowptr[i] = c + incl - x; cursor[i] = c + incl - x; }
    if (tid == 1023) carry = c + incl;
    __syncthreads();
  }
  if (tid == 0) rowptr[NN] = carry;
}

__global__ void k_scatter(const int* __restrict__ ei, int* __restrict__ cursor,
                          int* __restrict__ csr)
{
  int e = blockIdx.x * 256 + threadIdx.x;
  if (e >= EE) return;
  int slot = atomicAdd(&cursor[ei[EE + e]], 1);
  csr[slot] = e;
}

// ---------------- embedding ----------------
__global__ void k_xf_table(const float* __restrict__ W_embed, const float* __restrict__ W_x,
                           float* __restrict__ T)
{
  int sp = threadIdx.x >> 6, o = threadIdx.x & 63;
  float acc = 0.0f;
  for (int c = 0; c < 64; ++c) acc += W_embed[sp*64 + c] * W_x[c*64 + o];
  T[threadIdx.x] = acc;
}

__global__ void k_embed(const int* __restrict__ species, const float* __restrict__ W_embed,
                        const float* __restrict__ T, float* __restrict__ s,
                        float* __restrict__ xf)
{
  int gid = blockIdx.x * 256 + threadIdx.x;
  if (gid >= NN * 64) return;
  int n = gid >> 6, c = gid & 63;
  int sp = species[n];
  s[gid]  = W_embed[sp*64 + c];
  xf[gid] = T[sp*64 + c];
}

// ---------------- per-layer: up-projection ----------------
__global__ void k_up(const float* __restrict__ s, const float* __restrict__ v,
                     const float* __restrict__ Wus, const float* __restrict__ Wuv,
                     float* __restrict__ s_up, float* __restrict__ v_up)
{
  int gid = blockIdx.x * 256 + threadIdx.x;
  if (gid >= NN * 64) return;
  int n = gid >> 6, o = gid & 63;
  const float* sn = s + n*64;
  float acc = 0.0f;
  for (int c = 0; c < 64; ++c) acc += sn[c] * Wus[c*64 + o];
  s_up[gid] = acc;
  #pragma unroll
  for (int m = 0; m < 3; ++m) {
    const float* vn = v + (n*3 + m)*64;
    float a = 0.0f;
    for (int c = 0; c < 64; ++c) a += vn[c] * Wuv[c*64 + o];
    v_up[(n*3 + m)*64 + o] = a;
  }
}

// ---------------- per-layer: gather (radial MLP + messages + aggregation) ----------------
// block = 1024 (16 waves), wave-per-node, 4-edge batches so Wr2/Wr3 LDS reads amortize 4x.
// LDS: weights 21120 floats + per-wave h1/h2 float4 buffers 16*512 floats = 117,248 B.
__global__ __launch_bounds__(1024, 1) void k_gather(
    const int* __restrict__ ei, const int* __restrict__ rowptr, const int* __restrict__ csr,
    const float* __restrict__ efeat, const float* __restrict__ y1A, const float* __restrict__ maskA,
    const float* __restrict__ s_up, const float* __restrict__ v_up,
    const float* __restrict__ Wr1, const float* __restrict__ br1,
    const float* __restrict__ Wr2, const float* __restrict__ br2,
    const float* __restrict__ Wr3,
    float* __restrict__ agg_s, float* __restrict__ agg_v)
{
  __shared__ float sm[29312];
  float* Wr1s = sm;            // 512
  float* br1s = sm + 512;      // 64
  float* Wr2s = sm + 576;      // 4096
  float* br2s = sm + 4672;     // 64
  float* Wr3s = sm + 4736;     // 16384
  float* hbuf = sm + 21120;    // 16 waves * 512 (h1:256 + h2:256)
  int tid = threadIdx.x;
  for (int i = tid; i < 512;   i += 1024) Wr1s[i] = Wr1[i];
  for (int i = tid; i < 64;    i += 1024) { br1s[i] = br1[i]; br2s[i] = br2[i]; }
  for (int i = tid; i < 4096;  i += 1024) Wr2s[i] = Wr2[i];
  for (int i = tid; i < 16384; i += 1024) Wr3s[i] = Wr3[i];
  __syncthreads();

  int w = tid >> 6, c = tid & 63;
  int r = blockIdx.x * 16 + w;
  if (r >= NN) return;
  int start = rowptr[r], end = rowptr[r + 1];
  float accs = 0.0f, av0 = 0.0f, av1 = 0.0f, av2 = 0.0f;
  float4* h1t4 = (float4*)(hbuf + w*512);        // [64] float4: h1 of 4 edges per k
  float4* h2t4 = (float4*)(hbuf + w*512 + 256);  // [64] float4
  const float inv_sqrt3 = 0.5773502691896258f;

  for (int idx = start; idx < end; idx += 4) {
    int ej[4]; float mkj[4];
    #pragma unroll
    for (int j = 0; j < 4; ++j) {
      int ii = idx + j;
      bool valid = ii < end;
      int e = csr[valid ? ii : start];
      ej[j] = e;
      mkj[j] = valid ? maskA[e] : 0.0f;
    }
    // node/geometry loads issued early; MLP math below hides their latency
    float yj[4][3], ssj[4], vvj[4][3];
    #pragma unroll
    for (int j = 0; j < 4; ++j) {
      int e = ej[j];
      int sn = ei[e];
      yj[j][0] = y1A[e*3+0]; yj[j][1] = y1A[e*3+1]; yj[j][2] = y1A[e*3+2];
      ssj[j] = s_up[sn*64 + c];
      vvj[j][0] = v_up[(sn*3+0)*64 + c];
      vvj[j][1] = v_up[(sn*3+1)*64 + c];
      vvj[j][2] = v_up[(sn*3+2)*64 + c];
    }
    // ---- h1 = silu(efeat @ Wr1 + b1) for 4 edges ----
    float hv[4];
    #pragma unroll
    for (int j = 0; j < 4; ++j) {
      const float4* fe4 = (const float4*)(efeat + (size_t)ej[j] * 8);
      float4 fa = fe4[0], fb = fe4[1];
      float h = br1s[c];
      h += fa.x*Wr1s[0*64+c]; h += fa.y*Wr1s[1*64+c];
      h += fa.z*Wr1s[2*64+c]; h += fa.w*Wr1s[3*64+c];
      h += fb.x*Wr1s[4*64+c]; h += fb.y*Wr1s[5*64+c];
      h += fb.z*Wr1s[6*64+c]; h += fb.w*Wr1s[7*64+c];
      hv[j] = silu_f(h);
    }
    h1t4[c] = make_float4(hv[0], hv[1], hv[2], hv[3]);  // wave-lockstep, no barrier
    // ---- h2 = silu(h1 @ Wr2 + b2): one Wr2 read serves 4 edges ----
    float a0 = br2s[c], a1 = a0, a2 = a0, a3 = a0;
    #pragma unroll 4
    for (int k = 0; k < 64; ++k) {
      float wkc = Wr2s[k*64 + c];
      float4 hk = h1t4[k];   // broadcast b128
      a0 += hk.x*wkc; a1 += hk.y*wkc; a2 += hk.z*wkc; a3 += hk.w*wkc;
    }
    h2t4[c] = make_float4(silu_f(a0), silu_f(a1), silu_f(a2), silu_f(a3));
    // ---- wts = h2 @ Wr3 (4 paths), 4 edges per weight read ----
    float p0[4] = {0,0,0,0}, p1[4] = {0,0,0,0}, p2[4] = {0,0,0,0}, p3[4] = {0,0,0,0};
    #pragma unroll 2
    for (int k = 0; k < 64; ++k) {
      const float* wr = Wr3s + k*256;
      float wa = wr[c], wb = wr[64+c], wcc = wr[128+c], wd = wr[192+c];
      float4 hk = h2t4[k];   // broadcast b128
      p0[0]+=hk.x*wa;  p0[1]+=hk.y*wa;  p0[2]+=hk.z*wa;  p0[3]+=hk.w*wa;
      p1[0]+=hk.x*wb;  p1[1]+=hk.y*wb;  p1[2]+=hk.z*wb;  p1[3]+=hk.w*wb;
      p2[0]+=hk.x*wcc; p2[1]+=hk.y*wcc; p2[2]+=hk.z*wcc; p2[3]+=hk.w*wcc;
      p3[0]+=hk.x*wd;  p3[1]+=hk.y*wd;  p3[2]+=hk.z*wd;  p3[3]+=hk.w*wd;
    }
    // ---- equivariant message paths + accumulate ----
    #pragma unroll
    for (int j = 0; j < 4; ++j) {
      float mk = mkj[j];
      float w0 = p0[j]*mk, w1 = p1[j]*mk, w2 = p2[j]*mk, w3 = p3[j]*mk;
      float dot = vvj[j][0]*yj[j][0] + vvj[j][1]*yj[j][1] + vvj[j][2]*yj[j][2];
      accs += w0*ssj[j] + w1*dot*inv_sqrt3;
      av0  += w2*ssj[j]*yj[j][0] + w3*vvj[j][0];
      av1  += w2*ssj[j]*yj[j][1] + w3*vvj[j][1];
      av2  += w2*ssj[j]*yj[j][2] + w3*vvj[j][2];
    }
  }
  const float invavg = 1.0f / AVGN;
  agg_s[r*64 + c]          = accs * invavg;
  agg_v[(r*3 + 0)*64 + c]  = av0 * invavg;
  agg_v[(r*3 + 1)*64 + c]  = av1 * invavg;
  agg_v[(r*3 + 2)*64 + c]  = av2 * invavg;
}

// ---------------- per-layer: post (msg/sc/product matvecs + fused readout) ----------------
__global__ __launch_bounds__(512) void k_post(
    const float* __restrict__ agg_s, const float* __restrict__ agg_v,
    const float* __restrict__ xf, const int* __restrict__ species,
    float* __restrict__ s, float* __restrict__ v,
    const float* __restrict__ Wms, const float* __restrict__ Wmv,
    const float* __restrict__ Wscs, const float* __restrict__ Wscv,
    const float* __restrict__ Wps, const float* __restrict__ Wpv,
    const float* __restrict__ Wread, float* __restrict__ acc_out)
{
  __shared__ float tsb[8*64];
  __shared__ float tvb[8*3*64];
  __shared__ float vnb[8*3*64];
  int tid = threadIdx.x;
  int w = tid >> 6, c = tid & 63;
  int n = blockIdx.x * 8 + w;
  if (n >= NN) return;
  int sp = species[n];
  const float* as = agg_s + n*64;
  float ms = 0.0f;
  for (int k = 0; k < 64; ++k) ms += as[k] * Wms[k*64 + c];
  float xfc = xf[n*64 + c];
  tsb[w*64 + c] = xfc * ms;
  #pragma unroll
  for (int m = 0; m < 3; ++m) {
    const float* av = agg_v + (n*3 + m)*64;
    float mv = 0.0f;
    for (int k = 0; k < 64; ++k) mv += av[k] * Wmv[k*64 + c];
    tvb[(w*3 + m)*64 + c] = xfc * mv;
  }
  const float* snp = s + n*64;
  const float* Wsc_s = Wscs + sp*4096;
  float snew = 0.0f;
  {
    const float* tw = tsb + w*64;
    for (int k = 0; k < 64; ++k) snew += tw[k] * Wps[k*64 + c];
    for (int k = 0; k < 64; ++k) snew += snp[k] * Wsc_s[k*64 + c];
  }
  const float* Wsc_v = Wscv + sp*4096;
  float vnew[3];
  #pragma unroll
  for (int m = 0; m < 3; ++m) {
    const float* tw = tvb + (w*3 + m)*64;
    const float* vn = v + (n*3 + m)*64;
    float a = 0.0f;
    for (int k = 0; k < 64; ++k) a += tw[k] * Wpv[k*64 + c];
    for (int k = 0; k < 64; ++k) a += vn[k] * Wsc_v[k*64 + c];
    vnew[m] = a;
    vnb[(w*3 + m)*64 + c] = a;
  }
  s[n*64 + c] = snew;
  #pragma unroll
  for (int m = 0; m < 3; ++m) v[(n*3 + m)*64 + c] = vnew[m];
  if (c < 9) {
    int o3 = c / 3, m = c % 3;
    const float* vb = vnb + (w*3 + m)*64;
    const float* wr = Wread + o3*64;
    float a = 0.0f;
    for (int k = 0; k < 64; ++k) a += vb[k] * wr[k];
    acc_out[n*9 + c] += silu_f(a);
  }
}

// ---------------- final graph reduction ----------------
__global__ void k_final(const float* __restrict__ acc_out, float* __restrict__ out)
{
  __shared__ float red[256];
  int g = blockIdx.x / 9, j = blockIdx.x % 9;
  int tid = threadIdx.x;
  float a = 0.0f;
  for (int n = g*NPG + tid; n < (g + 1)*NPG; n += 256) a += acc_out[n*9 + j];
  red[tid] = a; __syncthreads();
  for (int off = 128; off > 0; off >>= 1) {
    if (tid < off) red[tid] += red[tid + off];
    __syncthreads();
  }
  if (tid == 0) out[g*9 + j] = red[0];
}

extern "C" void kernel_launch(void* const* d_in, const int* in_sizes, int n_in,
                              void* d_out, int out_size, void* d_ws, size_t ws_size,
                              hipStream_t stream)
{
  const float* pos     = (const float*)d_in[0];
  const float* cell    = (const float*)d_in[1];
  const float* Sij     = (const float*)d_in[2];
  const float* W_embed = (const float*)d_in[3];
  const float* W_x     = (const float*)d_in[4];
  const float* W_up_s  = (const float*)d_in[5];
  const float* W_up_v  = (const float*)d_in[6];
  const float* Wr1     = (const float*)d_in[7];
  const float* br1     = (const float*)d_in[8];
  const float* Wr2     = (const float*)d_in[9];
  const float* br2     = (const float*)d_in[10];
  const float* Wr3     = (const float*)d_in[11];
  const float* W_msg_s = (const float*)d_in[12];
  const float* W_msg_v = (const float*)d_in[13];
  const float* W_sc_s  = (const float*)d_in[14];
  const float* W_sc_v  = (const float*)d_in[15];
  const float* W_p_s   = (const float*)d_in[16];
  const float* W_p_v   = (const float*)d_in[17];
  const float* W_read  = (const float*)d_in[18];
  const int*   ei      = (const int*)d_in[19];
  const int*   batch   = (const int*)d_in[20];
  const int*   species = (const int*)d_in[21];
  float* out = (float*)d_out;

  char* ws = (char*)d_ws;
  size_t off = 0;
  auto alloc = [&](size_t bytes) -> void* {
    void* p = ws + off;
    off += (bytes + 255) & ~(size_t)255;
    return p;
  };
  float* y1A     = (float*)alloc((size_t)EE*3*4);
  float* efeat   = (float*)alloc((size_t)EE*8*4);
  float* maskA   = (float*)alloc((size_t)EE*4);
  float* sF      = (float*)alloc((size_t)NN*64*4);
  float* vF      = (float*)alloc((size_t)NN*192*4);
  float* xfF     = (float*)alloc((size_t)NN*64*4);
  float* s_up    = (float*)alloc((size_t)NN*64*4);
  float* v_up    = (float*)alloc((size_t)NN*192*4);
  float* agg_s   = (float*)alloc((size_t)NN*64*4);
  float* agg_v   = (float*)alloc((size_t)NN*192*4);
  float* acc_out = (float*)alloc((size_t)NN*9*4);
  float* T       = (float*)alloc(512*4);
  int* deg    = (int*)alloc((size_t)NN*4);
  int* rowptr = (int*)alloc((size_t)(NN+1)*4);
  int* cursor = (int*)alloc((size_t)NN*4);
  int* csr    = (int*)alloc((size_t)EE*4);

  hipMemsetAsync(deg, 0, (size_t)NN*4, stream);
  hipMemsetAsync(vF, 0, (size_t)NN*192*4, stream);
  hipMemsetAsync(acc_out, 0, (size_t)NN*9*4, stream);

  k_edge_geom<<<EE/256, 256, 0, stream>>>(pos, cell, Sij, ei, batch, y1A, efeat, maskA);
  k_count   <<<EE/256, 256, 0, stream>>>(ei, deg);
  k_scan    <<<1, 1024, 0, stream>>>(deg, rowptr, cursor);
  k_scatter <<<EE/256, 256, 0, stream>>>(ei, cursor, csr);
  k_xf_table<<<1, 512, 0, stream>>>(W_embed, W_x, T);
  k_embed   <<<NN*64/256, 256, 0, stream>>>(species, W_embed, T, sF, xfF);

  for (int l = 0; l < NLAYERS; ++l) {
    k_up<<<NN*64/256, 256, 0, stream>>>(sF, vF, W_up_s + l*4096, W_up_v + l*4096, s_up, v_up);
    k_gather<<<1250, 1024, 0, stream>>>(ei, rowptr, csr, efeat, y1A, maskA, s_up, v_up,
                                        Wr1 + l*512, br1 + l*64, Wr2 + l*4096, br2 + l*64,
                                        Wr3 + l*16384, agg_s, agg_v);
    k_post<<<2500, 512, 0, stream>>>(agg_s, agg_v, xfF, species, sF, vF,
                                     W_msg_s + l*4096, W_msg_v + l*4096,
                                     W_sc_s + l*32768, W_sc_v + l*32768,
                                     W_p_s + l*4096, W_p_v + l*4096,
                                     W_read + l*192, acc_out);
  }
  k_final<<<72, 256, 0, stream>>>(acc_out, out);
}

// Round 3
// 2837.691 us; speedup vs baseline: 1.9033x; 1.0413x over previous
//
#include <hip/hip_runtime.h>
#include <math.h>

#define NN 20000
#define GG 8
#define NPG 2500
#define EE 640000
#define CC 64
#define SSP 8
#define NBASIS 8
#define NLAYERS 3
#define CUTR 6.0f
#define AVGN 32.0f

typedef float v2f __attribute__((ext_vector_type(2)));
__device__ __forceinline__ v2f s2(float x){ return (v2f){x, x}; }
__device__ __forceinline__ float silu_f(float x){ return x / (1.0f + __expf(-x)); }

// ---------------- CSR degree count ----------------
__global__ void k_count(const int* __restrict__ ei, int* __restrict__ deg)
{
  int e = blockIdx.x * 256 + threadIdx.x;
  if (e >= EE) return;
  atomicAdd(&deg[ei[EE + e]], 1);
}

__global__ void k_scan(const int* __restrict__ deg, int* __restrict__ rowptr,
                       int* __restrict__ cursor)
{
  __shared__ int buf[1024];
  __shared__ int carry;
  int tid = threadIdx.x;
  if (tid == 0) carry = 0;
  __syncthreads();
  for (int base = 0; base < NN; base += 1024) {
    int i = base + tid;
    int x = (i < NN) ? deg[i] : 0;
    buf[tid] = x; __syncthreads();
    for (int off = 1; off < 1024; off <<= 1) {
      int t = (tid >= off) ? buf[tid - off] : 0;
      __syncthreads();
      buf[tid] += t;
      __syncthreads();
    }
    int incl = buf[tid];
    int c = carry;
    __syncthreads();
    if (i < NN) { rowptr[i] = c + incl - x; cursor[i] = c + incl - x; }
    if (tid == 1023) carry = c + incl;
    __syncthreads();
  }
  if (tid == 0) rowptr[NN] = carry;
}

// ---------------- fused geometry + CSR scatter (writes edge data in CSR order) ----------------
__global__ void k_geom_scatter(const float* __restrict__ pos, const float* __restrict__ cell,
                               const float* __restrict__ Sij, const int* __restrict__ ei,
                               const int* __restrict__ batch, int* __restrict__ cursor,
                               float* __restrict__ efeatP, float* __restrict__ y1mP,
                               int* __restrict__ sndP)
{
  int e = blockIdx.x * 256 + threadIdx.x;
  if (e >= EE) return;
  int snd = ei[e], rcv = ei[EE + e];
  int g = batch[snd];
  float s0 = Sij[e*3+0], s1 = Sij[e*3+1], s2_ = Sij[e*3+2];
  const float* cg = cell + g*9;
  float R[3];
  #pragma unroll
  for (int j = 0; j < 3; ++j) {
    float shift = s0*cg[0*3+j] + s1*cg[1*3+j] + s2_*cg[2*3+j];
    R[j] = (pos[rcv*3+j] - pos[snd*3+j] + shift) * (1.0f/CUTR);
  }
  float len = sqrtf(R[0]*R[0] + R[1]*R[1] + R[2]*R[2]);
  float mk   = (len > 0.0f) ? 1.0f : 0.0f;
  float safe = (len > 0.0f) ? len  : 1.0f;
  float inv  = 1.0f / safe;
  const float sqrt3 = 1.7320508075688772f;
  float x = safe;
  float env = (x < 1.0f) ? (1.0f - 6.0f*x*x + 8.0f*x*x*x - 3.0f*x*x*x*x) : 0.0f;
  float emk = env * mk;
  const float sqrt2 = 1.4142135623730951f;
  const float PI_F = 3.14159265358979323846f;
  float f[8];
  #pragma unroll
  for (int n = 1; n <= NBASIS; ++n)
    f[n-1] = sqrt2 * __sinf(PI_F * (float)n * safe) * inv * emk;
  int slot = atomicAdd(&cursor[rcv], 1);
  ((float4*)efeatP)[slot*2 + 0] = make_float4(f[0], f[1], f[2], f[3]);
  ((float4*)efeatP)[slot*2 + 1] = make_float4(f[4], f[5], f[6], f[7]);
  ((float4*)y1mP)[slot] = make_float4(sqrt3*R[0]*inv, sqrt3*R[1]*inv, sqrt3*R[2]*inv, mk);
  sndP[slot] = snd;
}

// ---------------- embedding ----------------
__global__ void k_xf_table(const float* __restrict__ W_embed, const float* __restrict__ W_x,
                           float* __restrict__ T)
{
  int sp = threadIdx.x >> 6, o = threadIdx.x & 63;
  float acc = 0.0f;
  for (int c = 0; c < 64; ++c) acc += W_embed[sp*64 + c] * W_x[c*64 + o];
  T[threadIdx.x] = acc;
}

__global__ void k_embed(const int* __restrict__ species, const float* __restrict__ W_embed,
                        const float* __restrict__ T, float* __restrict__ s,
                        float* __restrict__ xf)
{
  int gid = blockIdx.x * 256 + threadIdx.x;
  if (gid >= NN * 64) return;
  int n = gid >> 6, c = gid & 63;
  int sp = species[n];
  s[gid]  = W_embed[sp*64 + c];
  xf[gid] = T[sp*64 + c];
}

// ---------------- per-layer: up-projection ----------------
__global__ void k_up(const float* __restrict__ s, const float* __restrict__ v,
                     const float* __restrict__ Wus, const float* __restrict__ Wuv,
                     float* __restrict__ s_up, float* __restrict__ v_up)
{
  int gid = blockIdx.x * 256 + threadIdx.x;
  if (gid >= NN * 64) return;
  int n = gid >> 6, o = gid & 63;
  const float* sn = s + n*64;
  float acc = 0.0f;
  for (int c = 0; c < 64; ++c) acc += sn[c] * Wus[c*64 + o];
  s_up[gid] = acc;
  #pragma unroll
  for (int m = 0; m < 3; ++m) {
    const float* vn = v + (n*3 + m)*64;
    float a = 0.0f;
    for (int c = 0; c < 64; ++c) a += vn[c] * Wuv[c*64 + o];
    v_up[(n*3 + m)*64 + o] = a;
  }
}

// ---------------- per-layer: gather (radial MLP + messages + aggregation) ----------------
// block = 1024 (16 waves), wave-per-node, 4-edge batches; edge data pre-permuted to CSR order
// (sequential streams, no indirection); edge-pairs packed as float2 -> v_pk_fma_f32.
__global__ __launch_bounds__(1024, 1) void k_gather(
    const int* __restrict__ rowptr,
    const float* __restrict__ efeatP, const float* __restrict__ y1mP, const int* __restrict__ sndP,
    const float* __restrict__ s_up, const float* __restrict__ v_up,
    const float* __restrict__ Wr1, const float* __restrict__ br1,
    const float* __restrict__ Wr2, const float* __restrict__ br2,
    const float* __restrict__ Wr3,
    float* __restrict__ agg_s, float* __restrict__ agg_v)
{
  __shared__ float sm[29312];
  float* Wr1s = sm;            // 512
  float* br1s = sm + 512;      // 64
  float* Wr2s = sm + 576;      // 4096
  float* br2s = sm + 4672;     // 64
  float* Wr3s = sm + 4736;     // 16384
  float* hbuf = sm + 21120;    // 16 waves * 512 (h1:256 + h2:256)
  int tid = threadIdx.x;
  for (int i = tid; i < 512;   i += 1024) Wr1s[i] = Wr1[i];
  for (int i = tid; i < 64;    i += 1024) { br1s[i] = br1[i]; br2s[i] = br2[i]; }
  for (int i = tid; i < 4096;  i += 1024) Wr2s[i] = Wr2[i];
  for (int i = tid; i < 16384; i += 1024) Wr3s[i] = Wr3[i];
  __syncthreads();

  int w = tid >> 6, c = tid & 63;
  int r = blockIdx.x * 16 + w;
  if (r >= NN) return;
  int start = rowptr[r], end = rowptr[r + 1];
  float accs = 0.0f, av0 = 0.0f, av1 = 0.0f, av2 = 0.0f;
  float4* h1t4 = (float4*)(hbuf + w*512);        // [64] float4: h1 of 4 edges per k
  float4* h2t4 = (float4*)(hbuf + w*512 + 256);  // [64] float4
  const float inv_sqrt3 = 0.5773502691896258f;

  for (int idx = start; idx < end; idx += 4) {
    int slot[4]; float valid[4];
    #pragma unroll
    for (int j = 0; j < 4; ++j) {
      int ii = idx + j;
      bool ok = ii < end;
      slot[j] = ok ? ii : start;
      valid[j] = ok ? 1.0f : 0.0f;
    }
    // sequential broadcast streams (CSR-ordered): y1/mask, sender, node features
    float4 y1m[4]; float ssj[4], vvj[4][3];
    #pragma unroll
    for (int j = 0; j < 4; ++j) {
      y1m[j] = ((const float4*)y1mP)[slot[j]];
      int sn = sndP[slot[j]];
      ssj[j] = s_up[sn*64 + c];
      vvj[j][0] = v_up[(sn*3+0)*64 + c];
      vvj[j][1] = v_up[(sn*3+1)*64 + c];
      vvj[j][2] = v_up[(sn*3+2)*64 + c];
    }
    // ---- h1 = silu(efeat @ Wr1 + b1) for 4 edges ----
    float hv[4];
    #pragma unroll
    for (int j = 0; j < 4; ++j) {
      float4 fa = ((const float4*)efeatP)[slot[j]*2 + 0];
      float4 fb = ((const float4*)efeatP)[slot[j]*2 + 1];
      float h = br1s[c];
      h += fa.x*Wr1s[0*64+c]; h += fa.y*Wr1s[1*64+c];
      h += fa.z*Wr1s[2*64+c]; h += fa.w*Wr1s[3*64+c];
      h += fb.x*Wr1s[4*64+c]; h += fb.y*Wr1s[5*64+c];
      h += fb.z*Wr1s[6*64+c]; h += fb.w*Wr1s[7*64+c];
      hv[j] = silu_f(h);
    }
    h1t4[c] = make_float4(hv[0], hv[1], hv[2], hv[3]);  // wave-lockstep, no barrier
    // ---- h2 = silu(h1 @ Wr2 + b2): packed-pair FMA, one Wr2 read serves 4 edges ----
    v2f a01 = s2(br2s[c]), a23 = a01;
    #pragma unroll 4
    for (int k = 0; k < 64; ++k) {
      float wkc = Wr2s[k*64 + c];
      float4 hk = h1t4[k];   // broadcast b128
      a01 += (v2f){hk.x, hk.y} * s2(wkc);
      a23 += (v2f){hk.z, hk.w} * s2(wkc);
    }
    h2t4[c] = make_float4(silu_f(a01.x), silu_f(a01.y), silu_f(a23.x), silu_f(a23.y));
    // ---- wts = h2 @ Wr3 (4 paths), packed pairs, 4 edges per weight read ----
    v2f q0a = s2(0.f), q0b = q0a, q1a = q0a, q1b = q0a;
    v2f q2a = q0a, q2b = q0a, q3a = q0a, q3b = q0a;
    #pragma unroll 2
    for (int k = 0; k < 64; ++k) {
      const float* wr = Wr3s + k*256;
      float wa = wr[c], wb = wr[64+c], wcc = wr[128+c], wd = wr[192+c];
      float4 hk = h2t4[k];   // broadcast b128
      v2f h01 = {hk.x, hk.y}, h23 = {hk.z, hk.w};
      q0a += h01*s2(wa);  q0b += h23*s2(wa);
      q1a += h01*s2(wb);  q1b += h23*s2(wb);
      q2a += h01*s2(wcc); q2b += h23*s2(wcc);
      q3a += h01*s2(wd);  q3b += h23*s2(wd);
    }
    float p0[4] = {q0a.x, q0a.y, q0b.x, q0b.y};
    float p1[4] = {q1a.x, q1a.y, q1b.x, q1b.y};
    float p2[4] = {q2a.x, q2a.y, q2b.x, q2b.y};
    float p3[4] = {q3a.x, q3a.y, q3b.x, q3b.y};
    // ---- equivariant message paths + accumulate ----
    #pragma unroll
    for (int j = 0; j < 4; ++j) {
      float mk = y1m[j].w * valid[j];
      float w0 = p0[j]*mk, w1 = p1[j]*mk, w2 = p2[j]*mk, w3 = p3[j]*mk;
      float dot = vvj[j][0]*y1m[j].x + vvj[j][1]*y1m[j].y + vvj[j][2]*y1m[j].z;
      accs += w0*ssj[j] + w1*dot*inv_sqrt3;
      av0  += w2*ssj[j]*y1m[j].x + w3*vvj[j][0];
      av1  += w2*ssj[j]*y1m[j].y + w3*vvj[j][1];
      av2  += w2*ssj[j]*y1m[j].z + w3*vvj[j][2];
    }
  }
  const float invavg = 1.0f / AVGN;
  agg_s[r*64 + c]          = accs * invavg;
  agg_v[(r*3 + 0)*64 + c]  = av0 * invavg;
  agg_v[(r*3 + 1)*64 + c]  = av1 * invavg;
  agg_v[(r*3 + 2)*64 + c]  = av2 * invavg;
}

// ---------------- per-layer: post (msg/sc/product matvecs + fused readout) ----------------
__global__ __launch_bounds__(512) void k_post(
    const float* __restrict__ agg_s, const float* __restrict__ agg_v,
    const float* __restrict__ xf, const int* __restrict__ species,
    float* __restrict__ s, float* __restrict__ v,
    const float* __restrict__ Wms, const float* __restrict__ Wmv,
    const float* __restrict__ Wscs, const float* __restrict__ Wscv,
    const float* __restrict__ Wps, const float* __restrict__ Wpv,
    const float* __restrict__ Wread, float* __restrict__ acc_out)
{
  __shared__ float tsb[8*64];
  __shared__ float tvb[8*3*64];
  __shared__ float vnb[8*3*64];
  int tid = threadIdx.x;
  int w = tid >> 6, c = tid & 63;
  int n = blockIdx.x * 8 + w;
  if (n >= NN) return;
  int sp = species[n];
  const float* as = agg_s + n*64;
  float ms = 0.0f;
  for (int k = 0; k < 64; ++k) ms += as[k] * Wms[k*64 + c];
  float xfc = xf[n*64 + c];
  tsb[w*64 + c] = xfc * ms;
  #pragma unroll
  for (int m = 0; m < 3; ++m) {
    const float* av = agg_v + (n*3 + m)*64;
    float mv = 0.0f;
    for (int k = 0; k < 64; ++k) mv += av[k] * Wmv[k*64 + c];
    tvb[(w*3 + m)*64 + c] = xfc * mv;
  }
  const float* snp = s + n*64;
  const float* Wsc_s = Wscs + sp*4096;
  float snew = 0.0f;
  {
    const float* tw = tsb + w*64;
    for (int k = 0; k < 64; ++k) snew += tw[k] * Wps[k*64 + c];
    for (int k = 0; k < 64; ++k) snew += snp[k] * Wsc_s[k*64 + c];
  }
  const float* Wsc_v = Wscv + sp*4096;
  float vnew[3];
  #pragma unroll
  for (int m = 0; m < 3; ++m) {
    const float* tw = tvb + (w*3 + m)*64;
    const float* vn = v + (n*3 + m)*64;
    float a = 0.0f;
    for (int k = 0; k < 64; ++k) a += tw[k] * Wpv[k*64 + c];
    for (int k = 0; k < 64; ++k) a += vn[k] * Wsc_v[k*64 + c];
    vnew[m] = a;
    vnb[(w*3 + m)*64 + c] = a;
  }
  s[n*64 + c] = snew;
  #pragma unroll
  for (int m = 0; m < 3; ++m) v[(n*3 + m)*64 + c] = vnew[m];
  if (c < 9) {
    int o3 = c / 3, m = c % 3;
    const float* vb = vnb + (w*3 + m)*64;
    const float* wr = Wread + o3*64;
    float a = 0.0f;
    for (int k = 0; k < 64; ++k) a += vb[k] * wr[k];
    acc_out[n*9 + c] += silu_f(a);
  }
}

// ---------------- final graph reduction ----------------
__global__ void k_final(const float* __restrict__ acc_out, float* __restrict__ out)
{
  __shared__ float red[256];
  int g = blockIdx.x / 9, j = blockIdx.x % 9;
  int tid = threadIdx.x;
  float a = 0.0f;
  for (int n = g*NPG + tid; n < (g + 1)*NPG; n += 256) a += acc_out[n*9 + j];
  red[tid] = a; __syncthreads();
  for (int off = 128; off > 0; off >>= 1) {
    if (tid < off) red[tid] += red[tid + off];
    __syncthreads();
  }
  if (tid == 0) out[g*9 + j] = red[0];
}

extern "C" void kernel_launch(void* const* d_in, const int* in_sizes, int n_in,
                              void* d_out, int out_size, void* d_ws, size_t ws_size,
                              hipStream_t stream)
{
  const float* pos     = (const float*)d_in[0];
  const float* cell    = (const float*)d_in[1];
  const float* Sij     = (const float*)d_in[2];
  const float* W_embed = (const float*)d_in[3];
  const float* W_x     = (const float*)d_in[4];
  const float* W_up_s  = (const float*)d_in[5];
  const float* W_up_v  = (const float*)d_in[6];
  const float* Wr1     = (const float*)d_in[7];
  const float* br1     = (const float*)d_in[8];
  const float* Wr2     = (const float*)d_in[9];
  const float* br2     = (const float*)d_in[10];
  const float* Wr3     = (const float*)d_in[11];
  const float* W_msg_s = (const float*)d_in[12];
  const float* W_msg_v = (const float*)d_in[13];
  const float* W_sc_s  = (const float*)d_in[14];
  const float* W_sc_v  = (const float*)d_in[15];
  const float* W_p_s   = (const float*)d_in[16];
  const float* W_p_v   = (const float*)d_in[17];
  const float* W_read  = (const float*)d_in[18];
  const int*   ei      = (const int*)d_in[19];
  const int*   batch   = (const int*)d_in[20];
  const int*   species = (const int*)d_in[21];
  float* out = (float*)d_out;

  char* ws = (char*)d_ws;
  size_t off = 0;
  auto alloc = [&](size_t bytes) -> void* {
    void* p = ws + off;
    off += (bytes + 255) & ~(size_t)255;
    return p;
  };
  float* efeatP  = (float*)alloc((size_t)EE*8*4);
  float* y1mP    = (float*)alloc((size_t)EE*4*4);
  int*   sndP    = (int*)alloc((size_t)EE*4);
  float* sF      = (float*)alloc((size_t)NN*64*4);
  float* vF      = (float*)alloc((size_t)NN*192*4);
  float* xfF     = (float*)alloc((size_t)NN*64*4);
  float* s_up    = (float*)alloc((size_t)NN*64*4);
  float* v_up    = (float*)alloc((size_t)NN*192*4);
  float* agg_s   = (float*)alloc((size_t)NN*64*4);
  float* agg_v   = (float*)alloc((size_t)NN*192*4);
  float* acc_out = (float*)alloc((size_t)NN*9*4);
  float* T       = (float*)alloc(512*4);
  int* deg    = (int*)alloc((size_t)NN*4);
  int* rowptr = (int*)alloc((size_t)(NN+1)*4);
  int* cursor = (int*)alloc((size_t)NN*4);

  hipMemsetAsync(deg, 0, (size_t)NN*4, stream);
  hipMemsetAsync(vF, 0, (size_t)NN*192*4, stream);
  hipMemsetAsync(acc_out, 0, (size_t)NN*9*4, stream);

  k_count<<<EE/256, 256, 0, stream>>>(ei, deg);
  k_scan <<<1, 1024, 0, stream>>>(deg, rowptr, cursor);
  k_geom_scatter<<<EE/256, 256, 0, stream>>>(pos, cell, Sij, ei, batch, cursor,
                                             efeatP, y1mP, sndP);
  k_xf_table<<<1, 512, 0, stream>>>(W_embed, W_x, T);
  k_embed   <<<NN*64/256, 256, 0, stream>>>(species, W_embed, T, sF, xfF);

  for (int l = 0; l < NLAYERS; ++l) {
    k_up<<<NN*64/256, 256, 0, stream>>>(sF, vF, W_up_s + l*4096, W_up_v + l*4096, s_up, v_up);
    k_gather<<<1250, 1024, 0, stream>>>(rowptr, efeatP, y1mP, sndP, s_up, v_up,
                                        Wr1 + l*512, br1 + l*64, Wr2 + l*4096, br2 + l*64,
                                        Wr3 + l*16384, agg_s, agg_v);
    k_post<<<2500, 512, 0, stream>>>(agg_s, agg_v, xfF, species, sF, vF,
                                     W_msg_s + l*4096, W_msg_v + l*4096,
                                     W_sc_s + l*32768, W_sc_v + l*32768,
                                     W_p_s + l*4096, W_p_v + l*4096,
                                     W_read + l*192, acc_out);
  }
  k_final<<<72, 256, 0, stream>>>(acc_out, out);
}